// Round 2
// baseline (695.495 us; speedup 1.0000x reference)
//
#include <hip/hip_runtime.h>

typedef _Float16 half8 __attribute__((ext_vector_type(8)));
typedef _Float16 half4 __attribute__((ext_vector_type(4)));
typedef float    f32x4 __attribute__((ext_vector_type(4)));

// Problem constants (B=8, S=8192, K=1024, N=1024)
constexpr int Mtot = 65536;   // B*S
constexpr int Ntot = 1024;
constexpr int Ktot = 1024;

constexpr int BM = 128, BN = 128, BK = 32;
constexpr int KT = Ktot / BK;     // 32 K-steps

__global__ __launch_bounds__(256, 2)
void q8lin_gemm_kernel(const float* __restrict__ X,
                       const float* __restrict__ CB,
                       const float* __restrict__ SCB,
                       const float* __restrict__ BIAS,
                       float* __restrict__ OUT)
{
    // Double-buffered fp16 tiles: 2*(128*32 + 128*32)*2B = 32 KiB
    __shared__ _Float16 As[2][BM][BK];
    __shared__ _Float16 Bs[2][BN][BK];

    // XCD-bijective swizzle (nwg = 4096, divisible by 8): each XCD gets a
    // contiguous chunk of logical tiles -> A-panel reuse lands in its L2.
    const int nwg   = gridDim.x;
    const int chunk = nwg >> 3;
    const int bid   = blockIdx.x;
    const int wg    = (bid & 7) * chunk + (bid >> 3);

    const int ntile = wg & 7;          // N/BN = 8 tiles (fastest -> A reuse)
    const int mtile = wg >> 3;
    const int brow  = mtile * BM;
    const int bcol  = ntile * BN;

    const int tid  = threadIdx.x;
    const int lane = tid & 63;
    const int wid  = tid >> 6;         // 4 waves: 2x2 grid of 64x64 outputs
    const int wm   = wid >> 1;
    const int wn   = wid & 1;

    const float* aBase = X  + brow * Ktot;
    const float* bBase = CB + bcol * Ktot;

    // Staging decomposition: per K-step each matrix tile = 128 rows x 32 k
    // fp32 = 1024 float4; 256 threads x 4 float4 each.
    // f = s*256 + tid -> row = s*32 + (tid>>3), c4 = tid&7 (8 float4 per row).
    const int c4 = tid & 7;
    const int r0 = tid >> 3;

    f32x4 acc[4][4];
#pragma unroll
    for (int m = 0; m < 4; ++m)
#pragma unroll
        for (int n = 0; n < 4; ++n)
            acc[m][n] = (f32x4)0.0f;

    float4 arg[4], brg[4];   // in-flight staging registers (static indexing)

    auto loadTiles = [&](int t) {
        const float* ap = aBase + t * BK + c4 * 4;
        const float* bp = bBase + t * BK + c4 * 4;
#pragma unroll
        for (int s = 0; s < 4; ++s) {
            const int row = r0 + s * 32;
            arg[s] = *(const float4*)(ap + row * Ktot);
            brg[s] = *(const float4*)(bp + row * Ktot);
        }
    };

    auto writeTiles = [&](int buf) {
#pragma unroll
        for (int s = 0; s < 4; ++s) {
            const int row = r0 + s * 32;
            half4 ha = { (_Float16)arg[s].x, (_Float16)arg[s].y,
                         (_Float16)arg[s].z, (_Float16)arg[s].w };
            half4 hb = { (_Float16)brg[s].x, (_Float16)brg[s].y,
                         (_Float16)brg[s].z, (_Float16)brg[s].w };
            *(half4*)&As[buf][row][c4 * 4] = ha;
            *(half4*)&Bs[buf][row][c4 * 4] = hb;
        }
    };

    // Prologue: stage tile 0
    loadTiles(0);
    writeTiles(0);
    __syncthreads();

    // Fragment addressing for mfma_f32_16x16x32_f16:
    //   A: lane holds row (lane&15), k = (lane>>4)*8 + j  (8 contiguous fp16)
    //   B (from CB^T): lane holds col-channel (lane&15), same contiguous k
    const int rA = lane & 15;
    const int ko = (lane >> 4) * 8;

    for (int t = 0; t < KT; ++t) {
        const int cur = t & 1;

        if (t + 1 < KT) loadTiles(t + 1);   // issue next loads early (T14-lite)

        half8 af[4], bf[4];
#pragma unroll
        for (int m = 0; m < 4; ++m)
            af[m] = *(const half8*)&As[cur][wm * 64 + m * 16 + rA][ko];
#pragma unroll
        for (int n = 0; n < 4; ++n)
            bf[n] = *(const half8*)&Bs[cur][wn * 64 + n * 16 + rA][ko];

#pragma unroll
        for (int m = 0; m < 4; ++m)
#pragma unroll
            for (int n = 0; n < 4; ++n)
                acc[m][n] = __builtin_amdgcn_mfma_f32_16x16x32_f16(
                    af[m], bf[n], acc[m][n], 0, 0, 0);

        if (t + 1 < KT) writeTiles(cur ^ 1);  // cvt + ds_write after compute
        __syncthreads();
    }

    // Epilogue: dequant scale + bias, fp32 store.
    // C/D layout (m89-verified): col = lane&15, row = (lane>>4)*4 + reg.
    const float inv127 = 1.0f / 127.0f;
#pragma unroll
    for (int n = 0; n < 4; ++n) {
        const int col = bcol + wn * 64 + n * 16 + rA;
        const float s  = SCB[col] * inv127;
        const float bb = BIAS[col];
#pragma unroll
        for (int m = 0; m < 4; ++m) {
            const int grow = brow + wm * 64 + m * 16 + ((lane >> 4) << 2);
            float* op = OUT + grow * Ntot + col;
#pragma unroll
            for (int j = 0; j < 4; ++j)
                op[j * Ntot] = acc[m][n][j] * s + bb;
        }
    }
}

extern "C" void kernel_launch(void* const* d_in, const int* in_sizes, int n_in,
                              void* d_out, int out_size, void* d_ws, size_t ws_size,
                              hipStream_t stream) {
    const float* X    = (const float*)d_in[0];   // [B*S, K] = [65536, 1024]
    const float* CB   = (const float*)d_in[1];   // [N, K]   = [1024, 1024]
    const float* SCB  = (const float*)d_in[2];   // [N]
    const float* BIAS = (const float*)d_in[3];   // [N]
    float* OUT = (float*)d_out;                  // [B*S, N]

    const int grid = (Mtot / BM) * (Ntot / BN);  // 512 * 8 = 4096
    q8lin_gemm_kernel<<<dim3(grid), dim3(256), 0, stream>>>(X, CB, SCB, BIAS, OUT);
}

// Round 6
// 635.216 us; speedup vs baseline: 1.0949x; 1.0949x over previous
//
#include <hip/hip_runtime.h>

typedef _Float16 half8 __attribute__((ext_vector_type(8)));
typedef _Float16 half4 __attribute__((ext_vector_type(4)));
typedef float    f32x4 __attribute__((ext_vector_type(4)));

// B=8, S=8192, K=1024, N=1024
constexpr int Mtot = 65536;   // B*S
constexpr int Ntot = 1024;
constexpr int Ktot = 1024;
constexpr int Mhalf = Mtot / 2;   // 32768 rows per variant

// ---------------------------------------------------------------------------
// Variant A: 256x256 tile, BK=64, 8 waves (2Mx4N), acc[8][4], 1 block/CU.
// LDK=72 halves (144 B rows): 16B-aligned rows (legal ds_read_b128),
// bank-step 4/row -> fragment rows spread over 8 distinct 4-bank spans.
// LDS: 2*(256*72)*2B*2 = 144 KiB.
// ---------------------------------------------------------------------------
namespace va {
constexpr int BM = 256, BN = 256, BK = 64;
constexpr int KT  = Ktot / BK;   // 16
constexpr int LDK = 72;

__global__ __launch_bounds__(512, 2)
void gemm_a(const float* __restrict__ X,
            const float* __restrict__ CB,
            const float* __restrict__ SCB,
            const float* __restrict__ BIAS,
            float* __restrict__ OUT)
{
    __shared__ _Float16 As[2][BM][LDK];
    __shared__ _Float16 Bs[2][BN][LDK];

    // XCD-bijective swizzle: nwg = 512, divisible by 8.
    const int nwg = gridDim.x;
    const int bid = blockIdx.x;
    const int wg  = (bid & 7) * (nwg >> 3) + (bid >> 3);

    const int ntile = wg & 3;          // 4 N-tiles fastest -> A-panel L2 reuse
    const int mtile = wg >> 2;         // 0..127
    const int brow = mtile * BM;       // within [0, Mhalf)
    const int bcol = ntile * BN;

    const int tid  = threadIdx.x;
    const int lane = tid & 63;
    const int wid  = tid >> 6;         // 8 waves: 2(M) x 4(N)
    const int wm   = wid >> 2;
    const int wn   = wid & 3;

    // Staging: tile = 256 rows x 64 fp32 = 4096 float4; 512 thr x 8.
    const int c4 = tid & 15;           // 16 float4 per row
    const int r0 = tid >> 4;           // rows r0 + 32*s
    const float* aBase = X  + (size_t)(brow + r0) * Ktot + c4 * 4;
    const float* bBase = CB + (size_t)(bcol + r0) * Ktot + c4 * 4;

    f32x4 acc[8][4];
#pragma unroll
    for (int m = 0; m < 8; ++m)
#pragma unroll
        for (int n = 0; n < 4; ++n)
            acc[m][n] = (f32x4)0.0f;

    float4 arg[8], brg[8];

    auto loadTiles = [&](int t) {
#pragma unroll
        for (int s = 0; s < 8; ++s) {
            arg[s] = *(const float4*)(aBase + (size_t)s * 32 * Ktot + t * BK);
            brg[s] = *(const float4*)(bBase + (size_t)s * 32 * Ktot + t * BK);
        }
    };

    auto writeTiles = [&](int buf) {
#pragma unroll
        for (int s = 0; s < 8; ++s) {
            const int row = r0 + s * 32;
            half4 ha = { (_Float16)arg[s].x, (_Float16)arg[s].y,
                         (_Float16)arg[s].z, (_Float16)arg[s].w };
            half4 hb = { (_Float16)brg[s].x, (_Float16)brg[s].y,
                         (_Float16)brg[s].z, (_Float16)brg[s].w };
            *(half4*)&As[buf][row][c4 * 4] = ha;
            *(half4*)&Bs[buf][row][c4 * 4] = hb;
        }
    };

    loadTiles(0);
    writeTiles(0);
    loadTiles(1);
    __syncthreads();

    const int rA = lane & 15;
    const int ko = (lane >> 4) * 8;

    for (int t = 0; t < KT; ++t) {
        const int cur = t & 1;

        if (t + 1 < KT) writeTiles(cur ^ 1);
        if (t + 2 < KT) loadTiles(t + 2);

#pragma unroll
        for (int ks = 0; ks < 2; ++ks) {
            const int kof = ks * 32 + ko;
            half8 af[8], bf[4];
#pragma unroll
            for (int m = 0; m < 8; ++m)
                af[m] = *(const half8*)&As[cur][wm * 128 + m * 16 + rA][kof];
#pragma unroll
            for (int n = 0; n < 4; ++n)
                bf[n] = *(const half8*)&Bs[cur][wn * 64 + n * 16 + rA][kof];
#pragma unroll
            for (int m = 0; m < 8; ++m)
#pragma unroll
                for (int n = 0; n < 4; ++n)
                    acc[m][n] = __builtin_amdgcn_mfma_f32_16x16x32_f16(
                        af[m], bf[n], acc[m][n], 0, 0, 0);
        }

        __syncthreads();
    }

    const float inv127 = 1.0f / 127.0f;
#pragma unroll
    for (int n = 0; n < 4; ++n) {
        const int col = bcol + wn * 64 + n * 16 + rA;
        const float s  = SCB[col] * inv127;
        const float bb = BIAS[col];
#pragma unroll
        for (int m = 0; m < 8; ++m) {
            const int grow = brow + wm * 128 + m * 16 + ((lane >> 4) << 2);
            float* op = OUT + (size_t)grow * Ntot + col;
#pragma unroll
            for (int j = 0; j < 4; ++j)
                op[(size_t)j * Ntot] = acc[m][n][j] * s + bb;
        }
    }
}
} // namespace va

// ---------------------------------------------------------------------------
// Variant B: 128x128 tile, BK=32, 4 waves (2Mx2N), acc[4][4] — the round-2
// measured kernel + LDS pad only. LDK=40 halves (80 B rows): 16B-aligned,
// bank-step 20/row. LDS: 2*(128*40)*2B*2 = 40 KiB -> 3-4 blocks/CU.
// ---------------------------------------------------------------------------
namespace vb {
constexpr int BM = 128, BN = 128, BK = 32;
constexpr int KT  = Ktot / BK;   // 32
constexpr int LDK = 40;

__global__ __launch_bounds__(256, 2)
void gemm_b(const float* __restrict__ X,
            const float* __restrict__ CB,
            const float* __restrict__ SCB,
            const float* __restrict__ BIAS,
            float* __restrict__ OUT)
{
    __shared__ _Float16 As[2][BM][LDK];
    __shared__ _Float16 Bs[2][BN][LDK];

    // XCD-bijective swizzle: nwg = 2048, divisible by 8.
    const int nwg = gridDim.x;
    const int bid = blockIdx.x;
    const int wg  = (bid & 7) * (nwg >> 3) + (bid >> 3);

    const int ntile = wg & 7;          // 8 N-tiles fastest
    const int mtile = wg >> 3;         // 0..255
    const int brow = Mhalf + mtile * BM;   // second half of M
    const int bcol = ntile * BN;

    const int tid  = threadIdx.x;
    const int lane = tid & 63;
    const int wid  = tid >> 6;         // 4 waves: 2x2
    const int wm   = wid >> 1;
    const int wn   = wid & 1;

    // Staging: tile = 128 rows x 32 fp32 = 1024 float4; 256 thr x 4.
    const int c4 = tid & 7;            // 8 float4 per row
    const int r0 = tid >> 3;           // rows r0 + 32*s
    const float* aBase = X  + (size_t)(brow + r0) * Ktot + c4 * 4;
    const float* bBase = CB + (size_t)(bcol + r0) * Ktot + c4 * 4;

    f32x4 acc[4][4];
#pragma unroll
    for (int m = 0; m < 4; ++m)
#pragma unroll
        for (int n = 0; n < 4; ++n)
            acc[m][n] = (f32x4)0.0f;

    float4 arg[4], brg[4];

    auto loadTiles = [&](int t) {
#pragma unroll
        for (int s = 0; s < 4; ++s) {
            arg[s] = *(const float4*)(aBase + (size_t)s * 32 * Ktot + t * BK);
            brg[s] = *(const float4*)(bBase + (size_t)s * 32 * Ktot + t * BK);
        }
    };

    auto writeTiles = [&](int buf) {
#pragma unroll
        for (int s = 0; s < 4; ++s) {
            const int row = r0 + s * 32;
            half4 ha = { (_Float16)arg[s].x, (_Float16)arg[s].y,
                         (_Float16)arg[s].z, (_Float16)arg[s].w };
            half4 hb = { (_Float16)brg[s].x, (_Float16)brg[s].y,
                         (_Float16)brg[s].z, (_Float16)brg[s].w };
            *(half4*)&As[buf][row][c4 * 4] = ha;
            *(half4*)&Bs[buf][row][c4 * 4] = hb;
        }
    };

    loadTiles(0);
    writeTiles(0);
    loadTiles(1);
    __syncthreads();

    const int rA = lane & 15;
    const int ko = (lane >> 4) * 8;

    for (int t = 0; t < KT; ++t) {
        const int cur = t & 1;

        if (t + 1 < KT) writeTiles(cur ^ 1);
        if (t + 2 < KT) loadTiles(t + 2);

        half8 af[4], bf[4];
#pragma unroll
        for (int m = 0; m < 4; ++m)
            af[m] = *(const half8*)&As[cur][wm * 64 + m * 16 + rA][ko];
#pragma unroll
        for (int n = 0; n < 4; ++n)
            bf[n] = *(const half8*)&Bs[cur][wn * 64 + n * 16 + rA][ko];

#pragma unroll
        for (int m = 0; m < 4; ++m)
#pragma unroll
            for (int n = 0; n < 4; ++n)
                acc[m][n] = __builtin_amdgcn_mfma_f32_16x16x32_f16(
                    af[m], bf[n], acc[m][n], 0, 0, 0);

        __syncthreads();
    }

    const float inv127 = 1.0f / 127.0f;
#pragma unroll
    for (int n = 0; n < 4; ++n) {
        const int col = bcol + wn * 64 + n * 16 + rA;
        const float s  = SCB[col] * inv127;
        const float bb = BIAS[col];
#pragma unroll
        for (int m = 0; m < 4; ++m) {
            const int grow = brow + wm * 64 + m * 16 + ((lane >> 4) << 2);
            float* op = OUT + (size_t)grow * Ntot + col;
#pragma unroll
            for (int j = 0; j < 4; ++j)
                op[(size_t)j * Ntot] = acc[m][n][j] * s + bb;
        }
    }
}
} // namespace vb

extern "C" void kernel_launch(void* const* d_in, const int* in_sizes, int n_in,
                              void* d_out, int out_size, void* d_ws, size_t ws_size,
                              hipStream_t stream) {
    const float* X    = (const float*)d_in[0];   // [65536, 1024]
    const float* CB   = (const float*)d_in[1];   // [1024, 1024]
    const float* SCB  = (const float*)d_in[2];   // [1024]
    const float* BIAS = (const float*)d_in[3];   // [1024]
    float* OUT = (float*)d_out;                  // [65536, 1024]

    // Variant A: rows [0, 32768)   -> 128 M-tiles x 4 N-tiles = 512 wgs
    va::gemm_a<<<dim3(512), dim3(512), 0, stream>>>(X, CB, SCB, BIAS, OUT);
    // Variant B: rows [32768, 65536) -> 256 M-tiles x 8 N-tiles = 2048 wgs
    vb::gemm_b<<<dim3(2048), dim3(256), 0, stream>>>(X, CB, SCB, BIAS, OUT);
}

// Round 7
// 584.308 us; speedup vs baseline: 1.1903x; 1.0871x over previous
//
#include <hip/hip_runtime.h>

typedef _Float16 half8 __attribute__((ext_vector_type(8)));
typedef _Float16 half4 __attribute__((ext_vector_type(4)));
typedef float    f32x4 __attribute__((ext_vector_type(4)));

// B=8, S=8192, K=1024, N=1024
constexpr int Mtot = 65536, Ntot = 1024, Ktot = 1024;
constexpr int BM = 256, BN = 256, BK = 64;
constexpr int KT = Ktot / BK;          // 16 K-tiles
constexpr int MT = Mtot / BM;          // 256 M-tiles
constexpr int NT = Ntot / BN;          // 4 N-tiles

// Packed fp16 layout: [tile][kt][kh][1024 cells x 16B]. One cell = 8 halves
// of row r, k-range kh*32 + hi*8. Swizzle: cell(r,hi) = r*4 + (hi ^ ((r>>1)&3)).
// -> GEMM ds_read_b128 of a 16-lane fragment group touches all 32 banks
//    uniformly (bank = (16r + 4(hi^q) + j) mod 32 covers 8 distinct 4-bank
//    slots x 2 lanes), and global_load_lds stages it LINEARLY (swizzle lives
//    in this source permutation, per rule #21).
constexpr size_t XH_BYTES  = (size_t)MT * KT * 2 * 1024 * 16;  // 128 MiB
constexpr size_t CBH_BYTES = (size_t)NT * KT * 2 * 1024 * 16;  // 2 MiB

// ---------------------------------------------------------------------------
// Prepass: fp32 [tiles*256][1024] -> packed swizzled fp16 cells.
// ---------------------------------------------------------------------------
__global__ __launch_bounds__(256)
void cvt_pack(const float* __restrict__ src, _Float16* __restrict__ dst)
{
    const int C     = blockIdx.x * 256 + threadIdx.x;
    const int tile  = C >> 15;            // 32768 cells per 256-row tile
    const int rem   = C & 32767;
    const int kt    = rem >> 11;          // 2048 cells per K-tile
    const int kh    = (rem >> 10) & 1;    // k-half
    const int off16 = rem & 1023;
    const int r     = off16 >> 2;
    const int hi    = (off16 & 3) ^ ((r >> 1) & 3);   // inverse of the swizzle
    const float* s  = src + (size_t)(tile * 256 + r) * Ktot + kt * 64 + kh * 32 + hi * 8;
    f32x4 a = *(const f32x4*)s;
    f32x4 b = *(const f32x4*)(s + 4);
    half8 h = { (_Float16)a[0], (_Float16)a[1], (_Float16)a[2], (_Float16)a[3],
                (_Float16)b[0], (_Float16)b[1], (_Float16)b[2], (_Float16)b[3] };
    *(half8*)(dst + (size_t)C * 8) = h;
}

// ---------------------------------------------------------------------------
// 8-phase 256x256 GEMM (T3+T4 counted vmcnt, T5 setprio, T2 via pre-swizzle).
// LDS 128 KiB: A[2 buf][2 kh][8192 halves] then B likewise at +32768 halves.
// Per K-tile: 4 phases (ks,mh); each: 8 ds_read_b128 + 2 global_load_lds
// stage-issues + 16 MFMA. vmcnt(4) at phases 2 & 4 only (never 0; last iter
// peeled with a final drain).
// ---------------------------------------------------------------------------
__global__ __launch_bounds__(512, 2)
void gemm8(const _Float16* __restrict__ Xh, const _Float16* __restrict__ CBh,
           const float* __restrict__ SCB,  const float* __restrict__ BIAS,
           float* __restrict__ OUT)
{
    __shared__ __align__(16) _Float16 lds[65536];   // 128 KiB

    // XCD-bijective swizzle: nwg = 1024 (divisible by 8).
    const int nwg = gridDim.x;
    const int bid = blockIdx.x;
    const int wg  = (bid & 7) * (nwg >> 3) + (bid >> 3);
    const int nt  = wg & 3;          // N fastest: A-panel reuse within XCD
    const int mt  = wg >> 2;
    const int brow = mt * BM;
    const int bcol = nt * BN;

    const int tid  = threadIdx.x;
    const int lane = tid & 63;
    const int wid  = tid >> 6;       // 8 waves: 2(M) x 4(N)
    const int wm   = wid >> 2;
    const int wn   = wid & 3;
    const int rA   = lane & 15;
    const int hi   = lane >> 4;
    const int sl   = hi ^ ((rA >> 1) & 3);           // per-lane swizzle sel

    // Fragment base offsets in halves: cell*8 = r*32 + sl*8.
    const int aBaseH = (wm * 128 + rA) * 32 + sl * 8;
    const int bBaseH = 32768 + (wn * 64 + rA) * 32 + sl * 8;

    f32x4 acc[8][4];
#pragma unroll
    for (int m = 0; m < 8; ++m)
#pragma unroll
        for (int n = 0; n < 4; ++n)
            acc[m][n] = (f32x4)0.0f;

    // Stage one k-half (16 KiB) = 2 global_load_lds per thread/wave.
    auto stageA = [&](int kt, int kh, int buf) {
        const _Float16* sp = Xh + (size_t)((mt * KT + kt) * 2 + kh) * 8192;
#pragma unroll
        for (int g = 0; g < 2; ++g) {
            const int cell = g * 512 + tid;
            __builtin_amdgcn_global_load_lds(
                (const __attribute__((address_space(1))) void*)(sp + (size_t)cell * 8),
                (__attribute__((address_space(3))) void*)(&lds[buf * 16384 + kh * 8192 + cell * 8]),
                16, 0, 0);
        }
    };
    auto stageB = [&](int kt, int kh, int buf) {
        const _Float16* sp = CBh + (size_t)((nt * KT + kt) * 2 + kh) * 8192;
#pragma unroll
        for (int g = 0; g < 2; ++g) {
            const int cell = g * 512 + tid;
            __builtin_amdgcn_global_load_lds(
                (const __attribute__((address_space(1))) void*)(sp + (size_t)cell * 8),
                (__attribute__((address_space(3))) void*)(&lds[32768 + buf * 16384 + kh * 8192 + cell * 8]),
                16, 0, 0);
        }
    };

    // One phase: ds-read frags; issue stage; barrier; MFMA (setprio); optional
    // counted vmcnt; barrier. vm: -1 none, 4 vmcnt(4), 0 vmcnt(0).
    auto phase = [&](int c, int ks, int mh, auto&& stageFn, int vm) {
        half8 af[4], bf[4];
        const int ab = c * 16384 + ks * 8192;
#pragma unroll
        for (int f = 0; f < 4; ++f)
            af[f] = *(const half8*)&lds[ab + aBaseH + mh * 2048 + f * 512];
#pragma unroll
        for (int n = 0; n < 4; ++n)
            bf[n] = *(const half8*)&lds[ab + bBaseH + n * 512];
        stageFn();
        __builtin_amdgcn_s_barrier();
        __builtin_amdgcn_s_setprio(1);
#pragma unroll
        for (int f = 0; f < 4; ++f)
#pragma unroll
            for (int n = 0; n < 4; ++n)
                acc[mh * 4 + f][n] = __builtin_amdgcn_mfma_f32_16x16x32_f16(
                    af[f], bf[n], acc[mh * 4 + f][n], 0, 0, 0);
        __builtin_amdgcn_s_setprio(0);
        if (vm == 4)      asm volatile("s_waitcnt vmcnt(4)" ::: "memory");
        else if (vm == 0) asm volatile("s_waitcnt vmcnt(0)" ::: "memory");
        __builtin_amdgcn_s_barrier();
        __builtin_amdgcn_sched_barrier(0);
    };

    // Prologue: K-tile 0 -> buf0. Retire kh0 (first 4 of 8 loads) only.
    stageA(0, 0, 0); stageB(0, 0, 0);
    stageA(0, 1, 0); stageB(0, 1, 0);
    asm volatile("s_waitcnt vmcnt(4)" ::: "memory");
    __builtin_amdgcn_s_barrier();
    __builtin_amdgcn_sched_barrier(0);

    // Steady state. Invariant at iter start: outstanding = kh1(t) [4 loads].
    for (int t = 0; t < KT - 1; ++t) {
        const int c = t & 1, nb = c ^ 1;
        phase(c, 0, 0, [&] { stageA(t + 1, 0, nb); }, -1);
        phase(c, 0, 1, [&] { stageB(t + 1, 0, nb); },  4);  // retires kh1(t)
        phase(c, 1, 0, [&] { stageA(t + 1, 1, nb); }, -1);
        phase(c, 1, 1, [&] { stageB(t + 1, 1, nb); },  4);  // retires kh0(t+1)
    }
    // Peeled last K-tile (t = 15, c = 1): no stage issues; drain kh1(15).
    phase(1, 0, 0, [] {}, -1);
    phase(1, 0, 1, [] {},  0);
    phase(1, 1, 0, [] {}, -1);
    phase(1, 1, 1, [] {}, -1);

    // Epilogue: dequant + bias. C/D: col = lane&15, row = hi*4 + reg.
    const float inv127 = 1.0f / 127.0f;
#pragma unroll
    for (int n = 0; n < 4; ++n) {
        const int col = bcol + wn * 64 + n * 16 + rA;
        const float s  = SCB[col] * inv127;
        const float bb = BIAS[col];
#pragma unroll
        for (int m = 0; m < 8; ++m) {
            const int grow = brow + wm * 128 + m * 16 + (hi << 2);
            float* op = OUT + (size_t)grow * Ntot + col;
#pragma unroll
            for (int j = 0; j < 4; ++j)
                op[(size_t)j * Ntot] = acc[m][n][j] * s + bb;
        }
    }
}

// ---------------------------------------------------------------------------
// Fallback (ws too small): round-2-measured 128x128 fp16 kernel, full M.
// ---------------------------------------------------------------------------
namespace fb {
constexpr int BMf = 128, BNf = 128, BKf = 32;
constexpr int KTf = Ktot / BKf;
constexpr int LDK = 40;

__global__ __launch_bounds__(256, 2)
void gemm_fb(const float* __restrict__ X, const float* __restrict__ CB,
             const float* __restrict__ SCB, const float* __restrict__ BIAS,
             float* __restrict__ OUT)
{
    __shared__ _Float16 As[2][BMf][LDK];
    __shared__ _Float16 Bs[2][BNf][LDK];

    const int nwg = gridDim.x;
    const int bid = blockIdx.x;
    const int wg  = (bid & 7) * (nwg >> 3) + (bid >> 3);
    const int ntile = wg & 7;
    const int mtile = wg >> 3;
    const int brow = mtile * BMf;
    const int bcol = ntile * BNf;

    const int tid = threadIdx.x, lane = tid & 63, wid = tid >> 6;
    const int wm = wid >> 1, wn = wid & 1;
    const int c4 = tid & 7, r0 = tid >> 3;
    const float* aBase = X  + (size_t)(brow + r0) * Ktot + c4 * 4;
    const float* bBase = CB + (size_t)(bcol + r0) * Ktot + c4 * 4;

    f32x4 acc[4][4];
#pragma unroll
    for (int m = 0; m < 4; ++m)
#pragma unroll
        for (int n = 0; n < 4; ++n) acc[m][n] = (f32x4)0.0f;

    float4 arg[4], brg[4];
    auto loadTiles = [&](int t) {
#pragma unroll
        for (int s = 0; s < 4; ++s) {
            arg[s] = *(const float4*)(aBase + (size_t)s * 32 * Ktot + t * BKf);
            brg[s] = *(const float4*)(bBase + (size_t)s * 32 * Ktot + t * BKf);
        }
    };
    auto writeTiles = [&](int buf) {
#pragma unroll
        for (int s = 0; s < 4; ++s) {
            const int row = r0 + s * 32;
            half4 ha = { (_Float16)arg[s].x, (_Float16)arg[s].y,
                         (_Float16)arg[s].z, (_Float16)arg[s].w };
            half4 hb = { (_Float16)brg[s].x, (_Float16)brg[s].y,
                         (_Float16)brg[s].z, (_Float16)brg[s].w };
            *(half4*)&As[buf][row][c4 * 4] = ha;
            *(half4*)&Bs[buf][row][c4 * 4] = hb;
        }
    };

    loadTiles(0); writeTiles(0); loadTiles(1);
    __syncthreads();
    const int rA = lane & 15, ko = (lane >> 4) * 8;

    for (int t = 0; t < KTf; ++t) {
        const int cur = t & 1;
        if (t + 1 < KTf) writeTiles(cur ^ 1);
        if (t + 2 < KTf) loadTiles(t + 2);
        half8 af[4], bf[4];
#pragma unroll
        for (int m = 0; m < 4; ++m) af[m] = *(const half8*)&As[cur][wm * 64 + m * 16 + rA][ko];
#pragma unroll
        for (int n = 0; n < 4; ++n) bf[n] = *(const half8*)&Bs[cur][wn * 64 + n * 16 + rA][ko];
#pragma unroll
        for (int m = 0; m < 4; ++m)
#pragma unroll
            for (int n = 0; n < 4; ++n)
                acc[m][n] = __builtin_amdgcn_mfma_f32_16x16x32_f16(af[m], bf[n], acc[m][n], 0, 0, 0);
        __syncthreads();
    }

    const float inv127 = 1.0f / 127.0f;
#pragma unroll
    for (int n = 0; n < 4; ++n) {
        const int col = bcol + wn * 64 + n * 16 + rA;
        const float s = SCB[col] * inv127;
        const float bb = BIAS[col];
#pragma unroll
        for (int m = 0; m < 4; ++m) {
            const int grow = brow + wm * 64 + m * 16 + ((lane >> 4) << 2);
            float* op = OUT + (size_t)grow * Ntot + col;
#pragma unroll
            for (int j = 0; j < 4; ++j) op[(size_t)j * Ntot] = acc[m][n][j] * s + bb;
        }
    }
}
} // namespace fb

extern "C" void kernel_launch(void* const* d_in, const int* in_sizes, int n_in,
                              void* d_out, int out_size, void* d_ws, size_t ws_size,
                              hipStream_t stream) {
    const float* X    = (const float*)d_in[0];   // [65536, 1024]
    const float* CB   = (const float*)d_in[1];   // [1024, 1024]
    const float* SCB  = (const float*)d_in[2];   // [1024]
    const float* BIAS = (const float*)d_in[3];   // [1024]
    float* OUT = (float*)d_out;                  // [65536, 1024]

    if (ws_size < XH_BYTES + CBH_BYTES) {
        fb::gemm_fb<<<dim3(4096), dim3(256), 0, stream>>>(X, CB, SCB, BIAS, OUT);
        return;
    }

    _Float16* Xh  = (_Float16*)d_ws;
    _Float16* CBh = (_Float16*)((char*)d_ws + XH_BYTES);

    // X: 256 tiles * 32768 cells / 256 thr = 32768 blocks; CB: 512 blocks.
    cvt_pack<<<dim3(32768), dim3(256), 0, stream>>>(X, Xh);
    cvt_pack<<<dim3(512),   dim3(256), 0, stream>>>(CB, CBh);
    gemm8<<<dim3(MT * NT), dim3(512), 0, stream>>>(Xh, CBh, SCB, BIAS, OUT);
}

// Round 10
// 584.101 us; speedup vs baseline: 1.1907x; 1.0004x over previous
//
#include <hip/hip_runtime.h>

typedef _Float16 half8 __attribute__((ext_vector_type(8)));
typedef _Float16 half4 __attribute__((ext_vector_type(4)));
typedef float    f32x4 __attribute__((ext_vector_type(4)));

// B=8, S=8192, K=1024, N=1024
constexpr int Mtot = 65536, Ntot = 1024, Ktot = 1024;
constexpr int BM = 256, BN = 256, BK = 64;
constexpr int KT = Ktot / BK;          // 16 K-tiles (32 halves of k=32)
constexpr int MT = Mtot / BM;          // 256
constexpr int NT = Ntot / BN;          // 4

// Packed fp16: [tile][kt][kh][1024 cells x 16B]; cell(r,hi) = r*4 + (hi^((r>>1)&3)),
// covering row r, k = kt*64 + kh*32 + hi*8. Swizzle lives in this source
// permutation (rule #21) so global_load_lds stages linearly and the GEMM's
// swizzled ds_read_b128 is bank-conflict-free (measured 0 in round 7).
constexpr size_t XH_BYTES  = (size_t)MT * KT * 2 * 1024 * 16;  // 128 MiB
constexpr size_t CBH_BYTES = (size_t)NT * KT * 2 * 1024 * 16;  // 2 MiB

// ---------------------------------------------------------------------------
// Prepass, source-linear: coalesced 32B reads; writes are 16B cells permuted
// only WITHIN 64B groups -> still line-coalesced.
// ---------------------------------------------------------------------------
__global__ __launch_bounds__(256)
void cvt_pack(const float* __restrict__ src, _Float16* __restrict__ dst)
{
    const int T = blockIdx.x * 256 + threadIdx.x;
    const float* s = src + (size_t)T * 8;
    f32x4 a = *(const f32x4*)s;
    f32x4 b = *(const f32x4*)(s + 4);
    half8 h = { (_Float16)a[0], (_Float16)a[1], (_Float16)a[2], (_Float16)a[3],
                (_Float16)b[0], (_Float16)b[1], (_Float16)b[2], (_Float16)b[3] };

    const int g    = T >> 7;            // global row (128 thr/row of 1024 floats)
    const int k0   = (T & 127) << 3;    // k offset of these 8 floats
    const int tile = g >> 8;
    const int r    = g & 255;
    const int kt   = k0 >> 6;
    const int kh   = (k0 >> 5) & 1;
    const int hi   = (k0 >> 3) & 3;
    const int c    = r * 4 + (hi ^ ((r >> 1) & 3));
    *(half8*)(dst + (size_t)((tile * KT + kt) * 2 + kh) * 8192 + (size_t)c * 8) = h;
}

// ---------------------------------------------------------------------------
// 256x256 GEMM, 4 phases/K-tile, 3-half-deep counted-vmcnt ring (m201 ledger).
// LDS 128 KiB: A ring = 4 slots x 8192 halves @0; B ring @32768.
// Half h = 2t+ks lives in slot h&3. Per tile t: issue stage(2t+3) at P0,
// stage(2t+4) at P2; vmcnt(8) at ends of P1/P3 retiring the half needed two
// phases later. Issue->wait distance = 6 phases. Tail peeled: 8,4 then 0.
// Slot-reuse safety: stage(h) writes slot h&3, whose last reader finished
// >=1 barrier before the issue point (P0: slot read in prev tile's ks=1;
// P2: slot read in this tile's ks=0, done at P1-end barrier).
// Cross-wave visibility: every wave executes its vmcnt BEFORE the closing
// barrier, so past the barrier ALL waves' loads for that half are retired.
// ---------------------------------------------------------------------------
__global__ __launch_bounds__(512, 2)
void gemm8(const _Float16* __restrict__ Xh, const _Float16* __restrict__ CBh,
           const float* __restrict__ SCB,  const float* __restrict__ BIAS,
           float* __restrict__ OUT)
{
    __shared__ __align__(16) _Float16 lds[65536];   // 128 KiB

    const int nwg = gridDim.x;                      // 1024, %8==0 -> bijective
    const int bid = blockIdx.x;
    const int wg  = (bid & 7) * (nwg >> 3) + (bid >> 3);
    const int nt  = wg & 3;                         // N fastest: A-panel L2 reuse
    const int mt  = wg >> 2;
    const int brow = mt * BM;
    const int bcol = nt * BN;

    const int tid  = threadIdx.x;
    const int lane = tid & 63;
    const int wid  = tid >> 6;                      // 8 waves: 2(M) x 4(N)
    const int wm   = wid >> 2;
    const int wn   = wid & 3;
    const int rA   = lane & 15;
    const int hi   = lane >> 4;
    const int sl   = hi ^ ((rA >> 1) & 3);          // per-lane swizzle selector

    const int aOff = (wm * 128 + rA) * 32 + sl * 8; // within-slot offsets
    const int bOff = (wn * 64  + rA) * 32 + sl * 8;

    f32x4 acc[8][4];
#pragma unroll
    for (int m = 0; m < 8; ++m)
#pragma unroll
        for (int n = 0; n < 4; ++n)
            acc[m][n] = (f32x4)0.0f;

    // Stage one half (A 16KiB + B 16KiB) = 4 gload_lds per thread.
    auto stageHalf = [&](int h) {
        const int kt = h >> 1, kh = h & 1, slot = h & 3;
        const _Float16* spA = Xh  + (size_t)((mt * KT + kt) * 2 + kh) * 8192;
        const _Float16* spB = CBh + (size_t)((nt * KT + kt) * 2 + kh) * 8192;
#pragma unroll
        for (int g = 0; g < 2; ++g) {
            const int cell = g * 512 + tid;
            __builtin_amdgcn_global_load_lds(
                (const __attribute__((address_space(1))) void*)(spA + (size_t)cell * 8),
                (__attribute__((address_space(3))) void*)(&lds[slot * 8192 + cell * 8]),
                16, 0, 0);
        }
#pragma unroll
        for (int g = 0; g < 2; ++g) {
            const int cell = g * 512 + tid;
            __builtin_amdgcn_global_load_lds(
                (const __attribute__((address_space(1))) void*)(spB + (size_t)cell * 8),
                (__attribute__((address_space(3))) void*)(&lds[32768 + slot * 8192 + cell * 8]),
                16, 0, 0);
        }
    };

    // One phase. loadB: read B-frags (mh==0) vs reuse regs (mh==1).
    // vm: -1 none, else s_waitcnt vmcnt(vm) before the closing barrier.
    half8 bfk[4];
    auto phase = [&](int slot, int mh, bool loadB, auto&& stageFn, int vm) {
        half8 af[4];
        const int ab = slot * 8192;
#pragma unroll
        for (int f = 0; f < 4; ++f)
            af[f] = *(const half8*)&lds[ab + aOff + mh * 2048 + f * 512];
        if (loadB) {
#pragma unroll
            for (int n = 0; n < 4; ++n)
                bfk[n] = *(const half8*)&lds[32768 + ab + bOff + n * 512];
        }
        stageFn();
        __builtin_amdgcn_s_barrier();
        __builtin_amdgcn_s_setprio(1);
#pragma unroll
        for (int f = 0; f < 4; ++f)
#pragma unroll
            for (int n = 0; n < 4; ++n)
                acc[mh * 4 + f][n] = __builtin_amdgcn_mfma_f32_16x16x32_f16(
                    af[f], bfk[n], acc[mh * 4 + f][n], 0, 0, 0);
        __builtin_amdgcn_s_setprio(0);
        if (vm == 8)      asm volatile("s_waitcnt vmcnt(8)" ::: "memory");
        else if (vm == 4) asm volatile("s_waitcnt vmcnt(4)" ::: "memory");
        else if (vm == 0) asm volatile("s_waitcnt vmcnt(0)" ::: "memory");
        __builtin_amdgcn_s_barrier();
        __builtin_amdgcn_sched_barrier(0);
    };

    // Prologue: stage halves 0,1,2 (12 loads); retire half 0 -> vmcnt(8).
    stageHalf(0); stageHalf(1); stageHalf(2);
    asm volatile("s_waitcnt vmcnt(8)" ::: "memory");
    __builtin_amdgcn_s_barrier();
    __builtin_amdgcn_sched_barrier(0);

    // Steady state (t = 0..13). Invariant at tile start: outstanding = {2t+1, 2t+2}.
    for (int t = 0; t < KT - 2; ++t) {
        const int s0 = (2 * t) & 3, s1 = (2 * t + 1) & 3;
        phase(s0, 0, true,  [&] { stageHalf(2 * t + 3); }, -1);
        phase(s0, 1, false, [] {},  8);   // retires half 2t+1
        phase(s1, 0, true,  [&] { stageHalf(2 * t + 4); }, -1);
        phase(s1, 1, false, [] {},  8);   // retires half 2t+2
    }
    // t = 14 (halves 28,29; slots 0,1): issue last half 31; taper 8 -> 4.
    phase(0, 0, true,  [&] { stageHalf(31); }, -1);
    phase(0, 1, false, [] {}, 8);         // retires 29
    phase(1, 0, true,  [] {}, -1);
    phase(1, 1, false, [] {}, 4);         // retires 30
    // t = 15 (halves 30,31; slots 2,3): drain 31 before its reads.
    phase(2, 0, true,  [] {}, -1);
    phase(2, 1, false, [] {}, 0);         // retires 31
    phase(3, 0, true,  [] {}, -1);
    phase(3, 1, false, [] {}, -1);

    // Epilogue: dequant + bias. C/D: col = lane&15, row = hi*4 + reg.
    const float inv127 = 1.0f / 127.0f;
#pragma unroll
    for (int n = 0; n < 4; ++n) {
        const int col = bcol + wn * 64 + n * 16 + rA;
        const float s  = SCB[col] * inv127;
        const float bb = BIAS[col];
#pragma unroll
        for (int m = 0; m < 8; ++m) {
            const int grow = brow + wm * 128 + m * 16 + (hi << 2);
            float* op = OUT + (size_t)grow * Ntot + col;
#pragma unroll
            for (int j = 0; j < 4; ++j)
                op[(size_t)j * Ntot] = acc[m][n][j] * s + bb;
        }
    }
}

// ---------------------------------------------------------------------------
// Fallback (ws too small): round-2-measured 128x128 fp16 kernel, full M.
// ---------------------------------------------------------------------------
namespace fb {
constexpr int BMf = 128, BNf = 128, BKf = 32;
constexpr int KTf = Ktot / BKf;
constexpr int LDK = 40;

__global__ __launch_bounds__(256, 2)
void gemm_fb(const float* __restrict__ X, const float* __restrict__ CB,
             const float* __restrict__ SCB, const float* __restrict__ BIAS,
             float* __restrict__ OUT)
{
    __shared__ _Float16 As[2][BMf][LDK];
    __shared__ _Float16 Bs[2][BNf][LDK];

    const int nwg = gridDim.x;
    const int bid = blockIdx.x;
    const int wg  = (bid & 7) * (nwg >> 3) + (bid >> 3);
    const int ntile = wg & 7;
    const int mtile = wg >> 3;
    const int brow = mtile * BMf;
    const int bcol = ntile * BNf;

    const int tid = threadIdx.x, lane = tid & 63, wid = tid >> 6;
    const int wm = wid >> 1, wn = wid & 1;
    const int c4 = tid & 7, r0 = tid >> 3;
    const float* aBase = X  + (size_t)(brow + r0) * Ktot + c4 * 4;
    const float* bBase = CB + (size_t)(bcol + r0) * Ktot + c4 * 4;

    f32x4 acc[4][4];
#pragma unroll
    for (int m = 0; m < 4; ++m)
#pragma unroll
        for (int n = 0; n < 4; ++n) acc[m][n] = (f32x4)0.0f;

    float4 arg[4], brg[4];
    auto loadTiles = [&](int t) {
#pragma unroll
        for (int s = 0; s < 4; ++s) {
            arg[s] = *(const float4*)(aBase + (size_t)s * 32 * Ktot + t * BKf);
            brg[s] = *(const float4*)(bBase + (size_t)s * 32 * Ktot + t * BKf);
        }
    };
    auto writeTiles = [&](int buf) {
#pragma unroll
        for (int s = 0; s < 4; ++s) {
            const int row = r0 + s * 32;
            half4 ha = { (_Float16)arg[s].x, (_Float16)arg[s].y,
                         (_Float16)arg[s].z, (_Float16)arg[s].w };
            half4 hb = { (_Float16)brg[s].x, (_Float16)brg[s].y,
                         (_Float16)brg[s].z, (_Float16)brg[s].w };
            *(half4*)&As[buf][row][c4 * 4] = ha;
            *(half4*)&Bs[buf][row][c4 * 4] = hb;
        }
    };

    loadTiles(0); writeTiles(0); loadTiles(1);
    __syncthreads();
    const int rA = lane & 15, ko = (lane >> 4) * 8;

    for (int t = 0; t < KTf; ++t) {
        const int cur = t & 1;
        if (t + 1 < KTf) writeTiles(cur ^ 1);
        if (t + 2 < KTf) loadTiles(t + 2);
        half8 af[4], bf[4];
#pragma unroll
        for (int m = 0; m < 4; ++m) af[m] = *(const half8*)&As[cur][wm * 64 + m * 16 + rA][ko];
#pragma unroll
        for (int n = 0; n < 4; ++n) bf[n] = *(const half8*)&Bs[cur][wn * 64 + n * 16 + rA][ko];
#pragma unroll
        for (int m = 0; m < 4; ++m)
#pragma unroll
            for (int n = 0; n < 4; ++n)
                acc[m][n] = __builtin_amdgcn_mfma_f32_16x16x32_f16(af[m], bf[n], acc[m][n], 0, 0, 0);
        __syncthreads();
    }

    const float inv127 = 1.0f / 127.0f;
#pragma unroll
    for (int n = 0; n < 4; ++n) {
        const int col = bcol + wn * 64 + n * 16 + rA;
        const float s = SCB[col] * inv127;
        const float bb = BIAS[col];
#pragma unroll
        for (int m = 0; m < 4; ++m) {
            const int grow = brow + wm * 64 + m * 16 + ((lane >> 4) << 2);
            float* op = OUT + (size_t)grow * Ntot + col;
#pragma unroll
            for (int j = 0; j < 4; ++j) op[(size_t)j * Ntot] = acc[m][n][j] * s + bb;
        }
    }
}
} // namespace fb

extern "C" void kernel_launch(void* const* d_in, const int* in_sizes, int n_in,
                              void* d_out, int out_size, void* d_ws, size_t ws_size,
                              hipStream_t stream) {
    const float* X    = (const float*)d_in[0];   // [65536, 1024]
    const float* CB   = (const float*)d_in[1];   // [1024, 1024]
    const float* SCB  = (const float*)d_in[2];   // [1024]
    const float* BIAS = (const float*)d_in[3];   // [1024]
    float* OUT = (float*)d_out;                  // [65536, 1024]

    if (ws_size < XH_BYTES + CBH_BYTES) {
        fb::gemm_fb<<<dim3(4096), dim3(256), 0, stream>>>(X, CB, SCB, BIAS, OUT);
        return;
    }

    _Float16* Xh  = (_Float16*)d_ws;
    _Float16* CBh = (_Float16*)((char*)d_ws + XH_BYTES);

    cvt_pack<<<dim3(32768), dim3(256), 0, stream>>>(X, Xh);   // 65536 rows
    cvt_pack<<<dim3(512),   dim3(256), 0, stream>>>(CB, CBh); // 1024 rows
    gemm8<<<dim3(MT * NT), dim3(512), 0, stream>>>(Xh, CBh, SCB, BIAS, OUT);
}

// Round 12
// 578.098 us; speedup vs baseline: 1.2031x; 1.0104x over previous
//
#include <hip/hip_runtime.h>

typedef _Float16 half8 __attribute__((ext_vector_type(8)));
typedef _Float16 half4 __attribute__((ext_vector_type(4)));
typedef float    f32x4 __attribute__((ext_vector_type(4)));

// B=8, S=8192, K=1024, N=1024
constexpr int Mtot = 65536, Ntot = 1024, Ktot = 1024;
constexpr int BM = 256, BN = 256, BK = 64;
constexpr int KT = Ktot / BK;          // 16 K-tiles = 32 halves (k=32 each)
constexpr int MT = Mtot / BM;          // 256
constexpr int NT = Ntot / BN;          // 4

// Packed fp16: [tile][kt][kh][1024 cells x 16B]; cell(r,hi) = r*4 + (hi^((r>>1)&3)).
// Swizzle lives in the source permutation (rule #21): global_load_lds stages
// linearly; GEMM's swizzled ds_read_b128 measured 0 bank conflicts (r7/r10).
constexpr size_t XH_BYTES  = (size_t)MT * KT * 2 * 1024 * 16;  // 128 MiB
constexpr size_t CBH_BYTES = (size_t)NT * KT * 2 * 1024 * 16;  // 2 MiB

// ---------------------------------------------------------------------------
// Prepass, source-linear: coalesced 32B reads; 16B-cell writes permuted only
// within 64B groups (line-coalesced).
// ---------------------------------------------------------------------------
__global__ __launch_bounds__(256)
void cvt_pack(const float* __restrict__ src, _Float16* __restrict__ dst)
{
    const int T = blockIdx.x * 256 + threadIdx.x;
    const float* s = src + (size_t)T * 8;
    f32x4 a = *(const f32x4*)s;
    f32x4 b = *(const f32x4*)(s + 4);
    half8 h = { (_Float16)a[0], (_Float16)a[1], (_Float16)a[2], (_Float16)a[3],
                (_Float16)b[0], (_Float16)b[1], (_Float16)b[2], (_Float16)b[3] };

    const int g    = T >> 7;
    const int k0   = (T & 127) << 3;
    const int tile = g >> 8;
    const int r    = g & 255;
    const int kt   = k0 >> 6;
    const int kh   = (k0 >> 5) & 1;
    const int hi   = (k0 >> 3) & 3;
    const int c    = r * 4 + (hi ^ ((r >> 1) & 3));
    *(half8*)(dst + (size_t)((tile * KT + kt) * 2 + kh) * 8192 + (size_t)c * 8) = h;
}

// ---------------------------------------------------------------------------
// 256x256 GEMM. 64 phases (32 halves x 2 m-halves), ONE barrier per phase.
// Register-double-buffered fragments: phase q prefetches frags(q+1) into the
// alternate buffer and MFMAs with frags read at q-1 -> LDS reads + staging
// VALU overlap the matrix-pipe drain.
//   A-frag buffers keyed on mh (a0: mh=0 phases, a1: mh=1), B on h&1 (b0,b1).
// vmcnt ledger (per wave, 4 loads per staged half):
//   steady tile t: stage(2t+3)@q=4t, stage(2t+4)@q=4t+2;
//   vmcnt(8)@q=4t retires half 2t+1 (first read q=4t+1);
//   vmcnt(8)@q=4t+2 retires half 2t+2. Tail: 8,4,0.
// Race safety (single barrier): MFMA(q) forces lgkm-retire of reads(q-1)
// before the q-end barrier; slot-overwrite stage(h) is issued >=2 barriers
// after the slot's last ds_read -> WAR ordered; RAW by vmcnt+barrier.
// ---------------------------------------------------------------------------
#define VMC(N) asm volatile("s_waitcnt vmcnt(" #N ")" ::: "memory")
#define BAR()  __builtin_amdgcn_s_barrier()

#define PREF_A(DST, slot, mh)                                              \
    {   const int _ab = (slot) * 8192 + aOff + (mh) * 2048;                \
        DST[0] = *(const half8*)&lds[_ab + 0 * 512];                       \
        DST[1] = *(const half8*)&lds[_ab + 1 * 512];                       \
        DST[2] = *(const half8*)&lds[_ab + 2 * 512];                       \
        DST[3] = *(const half8*)&lds[_ab + 3 * 512]; }

#define PREF_B(DST, slot)                                                  \
    {   const int _bb = 32768 + (slot) * 8192 + bOff;                      \
        DST[0] = *(const half8*)&lds[_bb + 0 * 512];                       \
        DST[1] = *(const half8*)&lds[_bb + 1 * 512];                       \
        DST[2] = *(const half8*)&lds[_bb + 2 * 512];                       \
        DST[3] = *(const half8*)&lds[_bb + 3 * 512]; }

#define MFMA16(AF, BF, MH)                                                 \
    __builtin_amdgcn_s_setprio(1);                                         \
    _Pragma("unroll")                                                      \
    for (int f = 0; f < 4; ++f)                                            \
        _Pragma("unroll")                                                  \
        for (int n = 0; n < 4; ++n)                                        \
            acc[(MH) * 4 + f][n] = __builtin_amdgcn_mfma_f32_16x16x32_f16( \
                AF[f], BF[n], acc[(MH) * 4 + f][n], 0, 0, 0);              \
    __builtin_amdgcn_s_setprio(0);

__global__ __launch_bounds__(512, 2)
void gemm8(const _Float16* __restrict__ Xh, const _Float16* __restrict__ CBh,
           const float* __restrict__ SCB,  const float* __restrict__ BIAS,
           float* __restrict__ OUT)
{
    __shared__ __align__(16) _Float16 lds[65536];   // 128 KiB

    const int nwg = gridDim.x;                      // 1024, %8==0 -> bijective
    const int bid = blockIdx.x;
    const int wg  = (bid & 7) * (nwg >> 3) + (bid >> 3);
    const int nt  = wg & 3;                         // N fastest: A-panel L2 reuse
    const int mt  = wg >> 2;
    const int brow = mt * BM;
    const int bcol = nt * BN;

    const int tid  = threadIdx.x;
    const int lane = tid & 63;
    const int wid  = tid >> 6;                      // 8 waves: 2(M) x 4(N)
    const int wm   = wid >> 2;
    const int wn   = wid & 3;
    const int rA   = lane & 15;
    const int hi   = lane >> 4;
    const int sl   = hi ^ ((rA >> 1) & 3);          // per-lane swizzle selector

    const int aOff = (wm * 128 + rA) * 32 + sl * 8;
    const int bOff = (wn * 64  + rA) * 32 + sl * 8;

    f32x4 acc[8][4];
#pragma unroll
    for (int m = 0; m < 8; ++m)
#pragma unroll
        for (int n = 0; n < 4; ++n)
            acc[m][n] = (f32x4)0.0f;

    // Hoisted staging addresses: per-thread global base + h*8192 per half.
    const _Float16* pAg = Xh  + (size_t)(mt * KT * 2) * 8192 + tid * 8;
    const _Float16* pBg = CBh + (size_t)(nt * KT * 2) * 8192 + tid * 8;

    auto stageHalf = [&](int h) {
        const int slot = h & 3;
        const _Float16* sA = pAg + (size_t)h * 8192;
        const _Float16* sB = pBg + (size_t)h * 8192;
        __builtin_amdgcn_global_load_lds(
            (const __attribute__((address_space(1))) void*)sA,
            (__attribute__((address_space(3))) void*)(&lds[slot * 8192 + tid * 8]), 16, 0, 0);
        __builtin_amdgcn_global_load_lds(
            (const __attribute__((address_space(1))) void*)(sA + 4096),
            (__attribute__((address_space(3))) void*)(&lds[slot * 8192 + 4096 + tid * 8]), 16, 0, 0);
        __builtin_amdgcn_global_load_lds(
            (const __attribute__((address_space(1))) void*)sB,
            (__attribute__((address_space(3))) void*)(&lds[32768 + slot * 8192 + tid * 8]), 16, 0, 0);
        __builtin_amdgcn_global_load_lds(
            (const __attribute__((address_space(1))) void*)(sB + 4096),
            (__attribute__((address_space(3))) void*)(&lds[32768 + slot * 8192 + 4096 + tid * 8]), 16, 0, 0);
    };

    half8 a0[4], a1[4], b0[4], b1[4];

    // Prologue: stage halves 0,1,2 (12 loads); retire half 0; read frags(q=0).
    stageHalf(0); stageHalf(1); stageHalf(2);
    VMC(8);
    BAR();
    PREF_A(a0, 0, 0); PREF_B(b0, 0);

    // Steady state: t = 0..13.
    for (int t = 0; t < KT - 2; ++t) {
        const int s0 = (2 * t) & 3, s1 = (2 * t + 1) & 3, s2 = (2 * t + 2) & 3;
        // q=4t+0: MFMA(h0,mh0) | pref a1<-(s0,mh1) | stage(2t+3) | ret 2t+1
        PREF_A(a1, s0, 1);
        stageHalf(2 * t + 3);
        MFMA16(a0, b0, 0);
        VMC(8); BAR();
        // q=4t+1: MFMA(h0,mh1) | pref a0,b1 <- s1
        PREF_A(a0, s1, 0); PREF_B(b1, s1);
        MFMA16(a1, b0, 1);
        BAR();
        // q=4t+2: MFMA(h1,mh0) | pref a1<-(s1,mh1) | stage(2t+4) | ret 2t+2
        PREF_A(a1, s1, 1);
        stageHalf(2 * t + 4);
        MFMA16(a0, b1, 0);
        VMC(8); BAR();
        // q=4t+3: MFMA(h1,mh1) | pref a0,b0 <- s2
        PREF_A(a0, s2, 0); PREF_B(b0, s2);
        MFMA16(a1, b1, 1);
        BAR();
    }
    // t=14: halves 28(slot0),29(slot1); last stage = half 31; taper 8 -> 4.
    PREF_A(a1, 0, 1); stageHalf(31); MFMA16(a0, b0, 0); VMC(8); BAR();
    PREF_A(a0, 1, 0); PREF_B(b1, 1); MFMA16(a1, b0, 1);         BAR();
    PREF_A(a1, 1, 1);                MFMA16(a0, b1, 0); VMC(4); BAR();
    PREF_A(a0, 2, 0); PREF_B(b0, 2); MFMA16(a1, b1, 1);         BAR();
    // t=15: halves 30(slot2),31(slot3); drain.
    PREF_A(a1, 2, 1);                MFMA16(a0, b0, 0); VMC(0); BAR();
    PREF_A(a0, 3, 0); PREF_B(b1, 3); MFMA16(a1, b0, 1);         BAR();
    PREF_A(a1, 3, 1);                MFMA16(a0, b1, 0);         BAR();
    MFMA16(a1, b1, 1);

    // Epilogue: dequant + bias. C/D: col = lane&15, row = hi*4 + reg.
    const float inv127 = 1.0f / 127.0f;
#pragma unroll
    for (int n = 0; n < 4; ++n) {
        const int col = bcol + wn * 64 + n * 16 + rA;
        const float s  = SCB[col] * inv127;
        const float bb = BIAS[col];
#pragma unroll
        for (int m = 0; m < 8; ++m) {
            const int grow = brow + wm * 128 + m * 16 + (hi << 2);
            float* op = OUT + (size_t)grow * Ntot + col;
#pragma unroll
            for (int j = 0; j < 4; ++j)
                op[(size_t)j * Ntot] = acc[m][n][j] * s + bb;
        }
    }
}

// ---------------------------------------------------------------------------
// Fallback (ws too small): round-2-measured 128x128 fp16 kernel, full M.
// ---------------------------------------------------------------------------
namespace fb {
constexpr int BMf = 128, BNf = 128, BKf = 32;
constexpr int KTf = Ktot / BKf;
constexpr int LDK = 40;

__global__ __launch_bounds__(256, 2)
void gemm_fb(const float* __restrict__ X, const float* __restrict__ CB,
             const float* __restrict__ SCB, const float* __restrict__ BIAS,
             float* __restrict__ OUT)
{
    __shared__ _Float16 As[2][BMf][LDK];
    __shared__ _Float16 Bs[2][BNf][LDK];

    const int nwg = gridDim.x;
    const int bid = blockIdx.x;
    const int wg  = (bid & 7) * (nwg >> 3) + (bid >> 3);
    const int ntile = wg & 7;
    const int mtile = wg >> 3;
    const int brow = mtile * BMf;
    const int bcol = ntile * BNf;

    const int tid = threadIdx.x, lane = tid & 63, wid = tid >> 6;
    const int wm = wid >> 1, wn = wid & 1;
    const int c4 = tid & 7, r0 = tid >> 3;
    const float* aBase = X  + (size_t)(brow + r0) * Ktot + c4 * 4;
    const float* bBase = CB + (size_t)(bcol + r0) * Ktot + c4 * 4;

    f32x4 acc[4][4];
#pragma unroll
    for (int m = 0; m < 4; ++m)
#pragma unroll
        for (int n = 0; n < 4; ++n) acc[m][n] = (f32x4)0.0f;

    float4 arg[4], brg[4];
    auto loadTiles = [&](int t) {
#pragma unroll
        for (int s = 0; s < 4; ++s) {
            arg[s] = *(const float4*)(aBase + (size_t)s * 32 * Ktot + t * BKf);
            brg[s] = *(const float4*)(bBase + (size_t)s * 32 * Ktot + t * BKf);
        }
    };
    auto writeTiles = [&](int buf) {
#pragma unroll
        for (int s = 0; s < 4; ++s) {
            const int row = r0 + s * 32;
            half4 ha = { (_Float16)arg[s].x, (_Float16)arg[s].y,
                         (_Float16)arg[s].z, (_Float16)arg[s].w };
            half4 hb = { (_Float16)brg[s].x, (_Float16)brg[s].y,
                         (_Float16)brg[s].z, (_Float16)brg[s].w };
            *(half4*)&As[buf][row][c4 * 4] = ha;
            *(half4*)&Bs[buf][row][c4 * 4] = hb;
        }
    };

    loadTiles(0); writeTiles(0); loadTiles(1);
    __syncthreads();
    const int rA = lane & 15, ko = (lane >> 4) * 8;

    for (int t = 0; t < KTf; ++t) {
        const int cur = t & 1;
        if (t + 1 < KTf) writeTiles(cur ^ 1);
        if (t + 2 < KTf) loadTiles(t + 2);
        half8 af[4], bf[4];
#pragma unroll
        for (int m = 0; m < 4; ++m) af[m] = *(const half8*)&As[cur][wm * 64 + m * 16 + rA][ko];
#pragma unroll
        for (int n = 0; n < 4; ++n) bf[n] = *(const half8*)&Bs[cur][wn * 64 + n * 16 + rA][ko];
#pragma unroll
        for (int m = 0; m < 4; ++m)
#pragma unroll
            for (int n = 0; n < 4; ++n)
                acc[m][n] = __builtin_amdgcn_mfma_f32_16x16x32_f16(af[m], bf[n], acc[m][n], 0, 0, 0);
        __syncthreads();
    }

    const float inv127 = 1.0f / 127.0f;
#pragma unroll
    for (int n = 0; n < 4; ++n) {
        const int col = bcol + wn * 64 + n * 16 + rA;
        const float s = SCB[col] * inv127;
        const float bb = BIAS[col];
#pragma unroll
        for (int m = 0; m < 4; ++m) {
            const int grow = brow + wm * 64 + m * 16 + ((lane >> 4) << 2);
            float* op = OUT + (size_t)grow * Ntot + col;
#pragma unroll
            for (int j = 0; j < 4; ++j) op[(size_t)j * Ntot] = acc[m][n][j] * s + bb;
        }
    }
}
} // namespace fb

extern "C" void kernel_launch(void* const* d_in, const int* in_sizes, int n_in,
                              void* d_out, int out_size, void* d_ws, size_t ws_size,
                              hipStream_t stream) {
    const float* X    = (const float*)d_in[0];   // [65536, 1024]
    const float* CB   = (const float*)d_in[1];   // [1024, 1024]
    const float* SCB  = (const float*)d_in[2];   // [1024]
    const float* BIAS = (const float*)d_in[3];   // [1024]
    float* OUT = (float*)d_out;                  // [65536, 1024]

    if (ws_size < XH_BYTES + CBH_BYTES) {
        fb::gemm_fb<<<dim3(4096), dim3(256), 0, stream>>>(X, CB, SCB, BIAS, OUT);
        return;
    }

    _Float16* Xh  = (_Float16*)d_ws;
    _Float16* CBh = (_Float16*)((char*)d_ws + XH_BYTES);

    cvt_pack<<<dim3(32768), dim3(256), 0, stream>>>(X, Xh);   // 65536 rows
    cvt_pack<<<dim3(512),   dim3(256), 0, stream>>>(CB, CBh); // 1024 rows
    gemm8<<<dim3(MT * NT), dim3(512), 0, stream>>>(Xh, CBh, SCB, BIAS, OUT);
}